// Round 1
// baseline (1112.099 us; speedup 1.0000x reference)
//
#include <hip/hip_runtime.h>

// ---------------------------------------------------------------------------
// NodeModelLtp: edge MLP (Linear(256->128)+ReLU, Linear(128->128), LN) ->
// scatter-mean over dst -> node MLP (Linear(384->128)+ReLU, Linear(128->128), LN)
// bf16 MFMA (16x16x32) with fp32 accumulate; weights register-resident,
// pre-transposed to [n][K] bf16 by prep_weights.
// summed buffer = d_out (node kernel reads its own tile rows before writing).
//
// R1 changes vs baseline (964 us):
//  - unsafeAtomicAdd for scatter (hardware global_atomic_add_f32, no CAS loop)
//  - h1s aliased into dead msg LDS region (+2 barriers): LDS 52224 -> 34816 B
//    => 4 blocks/CU; grid 512 -> 1024, __launch_bounds__(256,4)
//  - counts atomic moved to index-load phase
// ---------------------------------------------------------------------------

typedef __bf16 bf16x8 __attribute__((ext_vector_type(8)));
typedef float floatx4 __attribute__((ext_vector_type(4)));

__device__ __forceinline__ unsigned short f2bf(float f) {
    unsigned int u = __float_as_uint(f);
    u = u + 0x7FFFu + ((u >> 16) & 1u);   // RNE
    return (unsigned short)(u >> 16);
}
__device__ __forceinline__ unsigned int pk2(float a, float b) {
    return (unsigned int)f2bf(a) | ((unsigned int)f2bf(b) << 16);
}

// --- detect whether edge_idx buffer is int64 (odd 32-bit words all zero) ----
__global__ void detect_idx64(const unsigned int* __restrict__ idx, int* __restrict__ flag) {
    if (threadIdx.x == 0 && blockIdx.x == 0) {
        unsigned int o = 0;
        for (int i = 1; i < 64; i += 2) o |= idx[i];
        *flag = (o == 0u) ? 1 : 0;
    }
}

// --- convert + transpose weights to bf16 [n][K] -----------------------------
__global__ void prep_weights(const float* __restrict__ W1a, const float* __restrict__ W2a,
                             const float* __restrict__ W1b, const float* __restrict__ W2b,
                             unsigned short* __restrict__ w1aT, unsigned short* __restrict__ w2aT,
                             unsigned short* __restrict__ w1bT, unsigned short* __restrict__ w2bT) {
    int g = blockIdx.x * 256 + threadIdx.x;
    if (g < 32768) {                       // W1aT [128][256]
        int n = g >> 8, k = g & 255;
        w1aT[g] = f2bf(W1a[k * 128 + n]);
    } else if (g < 49152) {                // W2aT [128][128]
        int l = g - 32768; int n = l >> 7, k = l & 127;
        w2aT[l] = f2bf(W2a[k * 128 + n]);
    } else if (g < 98304) {                // W1bT [128][384]
        int l = g - 49152; int n = l / 384, k = l - n * 384;
        w1bT[l] = f2bf(W1b[k * 128 + n]);
    } else if (g < 114688) {               // W2bT [128][128]
        int l = g - 98304; int n = l >> 7, k = l & 127;
        w2bT[l] = f2bf(W2b[k * 128 + n]);
    }
}

// --- edge MLP + LayerNorm + atomic scatter ----------------------------------
__global__ __launch_bounds__(256, 4) void edge_mlp_scatter(
    const float* __restrict__ x, const void* __restrict__ eidx,
    const float* __restrict__ ea,
    const float* __restrict__ b1a, const float* __restrict__ b2a,
    const float* __restrict__ g1, const float* __restrict__ be1,
    const unsigned short* __restrict__ w1aT, const unsigned short* __restrict__ w2aT,
    float* __restrict__ summed, float* __restrict__ counts,
    const int* __restrict__ flag64, int E)
{
    // single aliased region: msg (33792 B) ⊇ h2 (33792 B) ⊇ h1 (17408 B)
    __shared__ union {
        unsigned short msg[64 * 264];   // 64 edges x (256 + 8 pad) bf16  = 33792 B
        unsigned short h1[64 * 136];    // 64 x (128 + 8 pad) bf16        = 17408 B
        float h2[64 * 132];             // 64 x (128 + 4 pad) fp32        = 33792 B
    } uA;
    __shared__ int lsRow[64], lsCol[64];
    __shared__ float sMean[64], sRstd[64];

    const int tid  = threadIdx.x;
    const int lane = tid & 63;
    const int wave = tid >> 6;
    const int quad = lane >> 4;
    const int lm   = lane & 15;
    const int ns   = wave * 32;        // this wave's 32-col n-slice

    // register-resident weight fragments (B-layout: [n=lane&15][k=quad*8+j])
    bf16x8 wf1[8][2], wf2[4][2];
#pragma unroll
    for (int kk = 0; kk < 8; kk++)
#pragma unroll
        for (int nt = 0; nt < 2; nt++)
            wf1[kk][nt] = *(const bf16x8*)(w1aT + (ns + nt * 16 + lm) * 256 + kk * 32 + quad * 8);
#pragma unroll
    for (int kk = 0; kk < 4; kk++)
#pragma unroll
        for (int nt = 0; nt < 2; nt++)
            wf2[kk][nt] = *(const bf16x8*)(w2aT + (ns + nt * 16 + lm) * 128 + kk * 32 + quad * 8);

    float b1v[2], b2v[2];
#pragma unroll
    for (int nt = 0; nt < 2; nt++) {
        b1v[nt] = b1a[ns + nt * 16 + lm];
        b2v[nt] = b2a[ns + nt * 16 + lm];
    }
    const int colT = tid & 127;
    const float gv = g1[colT], bev = be1[colT];
    const int use64 = *flag64;

    const int numTiles = (E + 63) >> 6;
    for (int t = blockIdx.x; t < numTiles; t += gridDim.x) {
        const int eb = t << 6;
        __syncthreads();  // B1: prev tile's scatter readers (h2 + lsRow) done
        if (tid < 64) {
            int e = eb + tid;
            const bool valid = (e < E);
            if (!valid) e = E - 1;
            int r, c;
            if (use64) { const long long* p = (const long long*)eidx; r = (int)p[e]; c = (int)p[E + e]; }
            else       { const int* p = (const int*)eidx;             r = p[e];      c = p[E + e]; }
            lsRow[tid] = r; lsCol[tid] = c;
            if (valid) unsafeAtomicAdd(counts + r, 1.f);
        }
        __syncthreads();  // B2: indices ready
        // ---- stage msg = [x[col] | edge_attr] as bf16 ----
        {
            const int rl = tid >> 5, l32 = tid & 31;
#pragma unroll
            for (int it = 0; it < 8; it++) {
                const int e = it * 8 + rl;
                int eg = eb + e; if (eg >= E) eg = E - 1;
                const float4 xv = ((const float4*)(x + (size_t)lsCol[e] * 128))[l32];
                const float4 av = ((const float4*)(ea + (size_t)eg * 128))[l32];
                *(unsigned int*)&uA.msg[e * 264 + l32 * 4]           = pk2(xv.x, xv.y);
                *(unsigned int*)&uA.msg[e * 264 + l32 * 4 + 2]       = pk2(xv.z, xv.w);
                *(unsigned int*)&uA.msg[e * 264 + 128 + l32 * 4]     = pk2(av.x, av.y);
                *(unsigned int*)&uA.msg[e * 264 + 128 + l32 * 4 + 2] = pk2(av.z, av.w);
            }
        }
        __syncthreads();  // B3: msg ready
        // ---- layer 1: [64x256] @ [256x128] ----
        floatx4 acc1[4][2] = {};
#pragma unroll
        for (int mt = 0; mt < 4; mt++)
#pragma unroll
            for (int kk = 0; kk < 8; kk++) {
                bf16x8 a = *(const bf16x8*)&uA.msg[(mt * 16 + lm) * 264 + kk * 32 + quad * 8];
                acc1[mt][0] = __builtin_amdgcn_mfma_f32_16x16x32_bf16(a, wf1[kk][0], acc1[mt][0], 0, 0, 0);
                acc1[mt][1] = __builtin_amdgcn_mfma_f32_16x16x32_bf16(a, wf1[kk][1], acc1[mt][1], 0, 0, 0);
            }
        __syncthreads();  // B4: all msg reads done (h1 aliases msg region)
        // bias + relu -> h1 (bf16), aliased into msg region
#pragma unroll
        for (int mt = 0; mt < 4; mt++)
#pragma unroll
            for (int nt = 0; nt < 2; nt++)
#pragma unroll
                for (int r = 0; r < 4; r++) {
                    const int row = mt * 16 + quad * 4 + r;
                    const int col = ns + nt * 16 + lm;
                    uA.h1[row * 136 + col] = f2bf(fmaxf(acc1[mt][nt][r] + b1v[nt], 0.f));
                }
        __syncthreads();  // B5: h1 ready
        // ---- layer 2: [64x128] @ [128x128] ----
        floatx4 acc2[4][2] = {};
#pragma unroll
        for (int mt = 0; mt < 4; mt++)
#pragma unroll
            for (int kk = 0; kk < 4; kk++) {
                bf16x8 a = *(const bf16x8*)&uA.h1[(mt * 16 + lm) * 136 + kk * 32 + quad * 8];
                acc2[mt][0] = __builtin_amdgcn_mfma_f32_16x16x32_bf16(a, wf2[kk][0], acc2[mt][0], 0, 0, 0);
                acc2[mt][1] = __builtin_amdgcn_mfma_f32_16x16x32_bf16(a, wf2[kk][1], acc2[mt][1], 0, 0, 0);
            }
        __syncthreads();  // B6: all h1 reads done (h2 overwrites h1 region)
        // + bias -> h2 fp32
#pragma unroll
        for (int mt = 0; mt < 4; mt++)
#pragma unroll
            for (int nt = 0; nt < 2; nt++)
#pragma unroll
                for (int r = 0; r < 4; r++) {
                    const int row = mt * 16 + quad * 4 + r;
                    const int col = ns + nt * 16 + lm;
                    uA.h2[row * 132 + col] = acc2[mt][nt][r] + b2v[nt];
                }
        __syncthreads();  // B7: h2 ready
        // ---- LayerNorm stats: 4 threads per edge ----
        {
            const int e = tid >> 2, q = tid & 3;
            const float4* hp = (const float4*)&uA.h2[e * 132 + q * 32];
            float s = 0.f, ss = 0.f;
#pragma unroll
            for (int i = 0; i < 8; i++) {
                float4 v = hp[i];
                s  += v.x + v.y + v.z + v.w;
                ss += v.x * v.x + v.y * v.y + v.z * v.z + v.w * v.w;
            }
            s  += __shfl_xor(s, 1);  s  += __shfl_xor(s, 2);
            ss += __shfl_xor(ss, 1); ss += __shfl_xor(ss, 2);
            if (q == 0) {
                float mean = s * (1.f / 128.f);
                float var  = ss * (1.f / 128.f) - mean * mean;
                sMean[e] = mean;
                sRstd[e] = rsqrtf(var + 1e-5f);
            }
        }
        __syncthreads();  // B8: stats ready
        // ---- normalized scatter-add (coalesced 128-col runs, HW fp32 atomics) ----
        {
            const int half = tid >> 7;
#pragma unroll
            for (int it = 0; it < 32; it++) {
                const int e = it * 2 + half;
                if (eb + e < E) {
                    float v = (uA.h2[e * 132 + colT] - sMean[e]) * sRstd[e] * gv + bev;
                    unsafeAtomicAdd(summed + (size_t)lsRow[e] * 128 + colT, v);
                }
            }
        }
    }
}

// --- node MLP + LayerNorm -> out --------------------------------------------
__global__ __launch_bounds__(256, 2) void node_mlp(
    const float* __restrict__ x, const float* __restrict__ u,
    const float* summed, const float* __restrict__ counts,
    const float* __restrict__ b1b, const float* __restrict__ b2b,
    const float* __restrict__ g2, const float* __restrict__ be2,
    const unsigned short* __restrict__ w1bT, const unsigned short* __restrict__ w2bT,
    float* out, int NN)
{
    __shared__ union {
        unsigned short msg[32 * 392];   // 32 nodes x (384 + 8 pad) bf16 = 25088 B
        float h2[32 * 132];             // 16896 B
    } uA;
    __shared__ unsigned short h1s[32 * 136];  // 8704 B
    __shared__ float sMean[32], sRstd[32];

    const int tid  = threadIdx.x;
    const int lane = tid & 63;
    const int wave = tid >> 6;
    const int quad = lane >> 4;
    const int lm   = lane & 15;
    const int ns   = wave * 32;

    bf16x8 wf1[12][2], wf2[4][2];
#pragma unroll
    for (int kk = 0; kk < 12; kk++)
#pragma unroll
        for (int nt = 0; nt < 2; nt++)
            wf1[kk][nt] = *(const bf16x8*)(w1bT + (ns + nt * 16 + lm) * 384 + kk * 32 + quad * 8);
#pragma unroll
    for (int kk = 0; kk < 4; kk++)
#pragma unroll
        for (int nt = 0; nt < 2; nt++)
            wf2[kk][nt] = *(const bf16x8*)(w2bT + (ns + nt * 16 + lm) * 128 + kk * 32 + quad * 8);

    float b1v[2], b2v[2];
#pragma unroll
    for (int nt = 0; nt < 2; nt++) {
        b1v[nt] = b1b[ns + nt * 16 + lm];
        b2v[nt] = b2b[ns + nt * 16 + lm];
    }
    const int colT = tid & 127;
    const float gv = g2[colT], bev = be2[colT];

    const int numTiles = (NN + 31) >> 5;
    for (int t = blockIdx.x; t < numTiles; t += gridDim.x) {
        const int nb = t << 5;
        __syncthreads();
        // ---- stage z = [x | summed/clip(counts,1) | u] as bf16 ----
        {
            const int rl = tid >> 5, l32 = tid & 31;
#pragma unroll
            for (int it = 0; it < 4; it++) {
                const int rloc = it * 8 + rl;
                int i = nb + rloc; if (i >= NN) i = NN - 1;
                const float4 xv = ((const float4*)(x + (size_t)i * 128))[l32];
                float4 sv = ((const float4*)(summed + (size_t)i * 128))[l32];
                const float inv = 1.f / fmaxf(counts[i], 1.f);
                sv.x *= inv; sv.y *= inv; sv.z *= inv; sv.w *= inv;
                const float4 uv = ((const float4*)(u + (size_t)i * 128))[l32];
                *(unsigned int*)&uA.msg[rloc * 392 + l32 * 4]           = pk2(xv.x, xv.y);
                *(unsigned int*)&uA.msg[rloc * 392 + l32 * 4 + 2]       = pk2(xv.z, xv.w);
                *(unsigned int*)&uA.msg[rloc * 392 + 128 + l32 * 4]     = pk2(sv.x, sv.y);
                *(unsigned int*)&uA.msg[rloc * 392 + 128 + l32 * 4 + 2] = pk2(sv.z, sv.w);
                *(unsigned int*)&uA.msg[rloc * 392 + 256 + l32 * 4]     = pk2(uv.x, uv.y);
                *(unsigned int*)&uA.msg[rloc * 392 + 256 + l32 * 4 + 2] = pk2(uv.z, uv.w);
            }
        }
        __syncthreads();
        // ---- layer 1: [32x384] @ [384x128] ----
        floatx4 acc1[2][2] = {};
#pragma unroll
        for (int mt = 0; mt < 2; mt++)
#pragma unroll
            for (int kk = 0; kk < 12; kk++) {
                bf16x8 a = *(const bf16x8*)&uA.msg[(mt * 16 + lm) * 392 + kk * 32 + quad * 8];
                acc1[mt][0] = __builtin_amdgcn_mfma_f32_16x16x32_bf16(a, wf1[kk][0], acc1[mt][0], 0, 0, 0);
                acc1[mt][1] = __builtin_amdgcn_mfma_f32_16x16x32_bf16(a, wf1[kk][1], acc1[mt][1], 0, 0, 0);
            }
#pragma unroll
        for (int mt = 0; mt < 2; mt++)
#pragma unroll
            for (int nt = 0; nt < 2; nt++)
#pragma unroll
                for (int r = 0; r < 4; r++) {
                    const int row = mt * 16 + quad * 4 + r;
                    const int col = ns + nt * 16 + lm;
                    h1s[row * 136 + col] = f2bf(fmaxf(acc1[mt][nt][r] + b1v[nt], 0.f));
                }
        __syncthreads();
        // ---- layer 2: [32x128] @ [128x128] ----
        floatx4 acc2[2][2] = {};
#pragma unroll
        for (int mt = 0; mt < 2; mt++)
#pragma unroll
            for (int kk = 0; kk < 4; kk++) {
                bf16x8 a = *(const bf16x8*)&h1s[(mt * 16 + lm) * 136 + kk * 32 + quad * 8];
                acc2[mt][0] = __builtin_amdgcn_mfma_f32_16x16x32_bf16(a, wf2[kk][0], acc2[mt][0], 0, 0, 0);
                acc2[mt][1] = __builtin_amdgcn_mfma_f32_16x16x32_bf16(a, wf2[kk][1], acc2[mt][1], 0, 0, 0);
            }
#pragma unroll
        for (int mt = 0; mt < 2; mt++)
#pragma unroll
            for (int nt = 0; nt < 2; nt++)
#pragma unroll
                for (int r = 0; r < 4; r++) {
                    const int row = mt * 16 + quad * 4 + r;
                    const int col = ns + nt * 16 + lm;
                    uA.h2[row * 132 + col] = acc2[mt][nt][r] + b2v[nt];
                }
        __syncthreads();
        // ---- LayerNorm stats: 8 threads per node ----
        {
            const int e = tid >> 3, q = tid & 7;
            const float4* hp = (const float4*)&uA.h2[e * 132 + q * 16];
            float s = 0.f, ss = 0.f;
#pragma unroll
            for (int i = 0; i < 4; i++) {
                float4 v = hp[i];
                s  += v.x + v.y + v.z + v.w;
                ss += v.x * v.x + v.y * v.y + v.z * v.z + v.w * v.w;
            }
            s  += __shfl_xor(s, 1);  s  += __shfl_xor(s, 2);  s  += __shfl_xor(s, 4);
            ss += __shfl_xor(ss, 1); ss += __shfl_xor(ss, 2); ss += __shfl_xor(ss, 4);
            if (q == 0) {
                float mean = s * (1.f / 128.f);
                float var  = ss * (1.f / 128.f) - mean * mean;
                sMean[e] = mean;
                sRstd[e] = rsqrtf(var + 1e-5f);
            }
        }
        __syncthreads();
        // ---- normalized coalesced store ----
        {
            const int half = tid >> 7;
#pragma unroll
            for (int it = 0; it < 16; it++) {
                const int rloc = it * 2 + half;
                const int i = nb + rloc;
                if (i < NN) {
                    float v = (uA.h2[rloc * 132 + colT] - sMean[rloc]) * sRstd[rloc] * gv + bev;
                    out[(size_t)i * 128 + colT] = v;
                }
            }
        }
    }
}

extern "C" void kernel_launch(void* const* d_in, const int* in_sizes, int n_in,
                              void* d_out, int out_size, void* d_ws, size_t ws_size,
                              hipStream_t stream)
{
    const float* x   = (const float*)d_in[0];
    const void*  eidx = d_in[1];
    const float* ea  = (const float*)d_in[2];
    const float* u   = (const float*)d_in[3];
    const float* W1a = (const float*)d_in[4];
    const float* b1a = (const float*)d_in[5];
    const float* W2a = (const float*)d_in[6];
    const float* b2a = (const float*)d_in[7];
    const float* g1  = (const float*)d_in[8];
    const float* be1 = (const float*)d_in[9];
    const float* W1b = (const float*)d_in[10];
    const float* b1b = (const float*)d_in[11];
    const float* W2b = (const float*)d_in[12];
    const float* b2b = (const float*)d_in[13];
    const float* g2  = (const float*)d_in[14];
    const float* be2 = (const float*)d_in[15];

    const int NN = in_sizes[0] / 128;
    const int E  = in_sizes[2] / 128;

    // workspace layout: counts[N] | flag | bf16 transposed weights
    float* counts = (float*)d_ws;
    int*   flag   = (int*)((char*)d_ws + (size_t)NN * 4);
    size_t woff   = (((size_t)NN * 4 + 4) + 15) & ~(size_t)15;
    unsigned short* w1aT = (unsigned short*)((char*)d_ws + woff);
    unsigned short* w2aT = w1aT + 128 * 256;
    unsigned short* w1bT = w2aT + 128 * 128;
    unsigned short* w2bT = w1bT + 128 * 384;

    float* outf = (float*)d_out;   // doubles as the scatter-sum buffer

    hipMemsetAsync(d_out, 0, (size_t)out_size * 4, stream);
    hipMemsetAsync(counts, 0, (size_t)NN * 4, stream);
    detect_idx64<<<1, 64, 0, stream>>>((const unsigned int*)eidx, flag);
    prep_weights<<<448, 256, 0, stream>>>(W1a, W2a, W1b, W2b, w1aT, w2aT, w1bT, w2bT);

    edge_mlp_scatter<<<1024, 256, 0, stream>>>(x, eidx, ea, b1a, b2a, g1, be1,
                                               w1aT, w2aT, outf, counts, flag, E);

    const int nodeTiles = (NN + 31) >> 5;
    node_mlp<<<nodeTiles, 256, 0, stream>>>(x, u, outf, counts, b1b, b2b, g2, be2,
                                            w1bT, w2bT, outf, NN);
}

// Round 2
// 1009.296 us; speedup vs baseline: 1.1019x; 1.1019x over previous
//
#include <hip/hip_runtime.h>

// ---------------------------------------------------------------------------
// NodeModelLtp: edge MLP (Linear(256->128)+ReLU, Linear(128->128), LN) ->
// scatter-mean over dst -> node MLP (Linear(384->128)+ReLU, Linear(128->128), LN)
// bf16 MFMA (16x16x32) with fp32 accumulate; weights register-resident,
// pre-transposed to [n][K] bf16 by prep_weights.
// summed buffer = d_out (node kernel reads its own tile rows before writing).
//
// R2 changes vs R1 (1112 us, regression):
//  - REVERT edge kernel to __launch_bounds__(256, 2): R1's (256,4) forced
//    VGPR 128->64, spilling the ~96 VGPRs of weight fragments to scratch
//    (FETCH_SIZE 388MB -> 1.09GB = per-tile spill refills). At 128 VGPR the
//    HW still allows 4 waves/SIMD, so occupancy stays ~45% with LDS 34816B
//    and grid 1024 — without the spill.
//  - KEEP: unsafeAtomicAdd scatter, h1 aliased into msg (LDS 34816 B), grid 1024.
// ---------------------------------------------------------------------------

typedef __bf16 bf16x8 __attribute__((ext_vector_type(8)));
typedef float floatx4 __attribute__((ext_vector_type(4)));

__device__ __forceinline__ unsigned short f2bf(float f) {
    unsigned int u = __float_as_uint(f);
    u = u + 0x7FFFu + ((u >> 16) & 1u);   // RNE
    return (unsigned short)(u >> 16);
}
__device__ __forceinline__ unsigned int pk2(float a, float b) {
    return (unsigned int)f2bf(a) | ((unsigned int)f2bf(b) << 16);
}

// --- detect whether edge_idx buffer is int64 (odd 32-bit words all zero) ----
__global__ void detect_idx64(const unsigned int* __restrict__ idx, int* __restrict__ flag) {
    if (threadIdx.x == 0 && blockIdx.x == 0) {
        unsigned int o = 0;
        for (int i = 1; i < 64; i += 2) o |= idx[i];
        *flag = (o == 0u) ? 1 : 0;
    }
}

// --- convert + transpose weights to bf16 [n][K] -----------------------------
__global__ void prep_weights(const float* __restrict__ W1a, const float* __restrict__ W2a,
                             const float* __restrict__ W1b, const float* __restrict__ W2b,
                             unsigned short* __restrict__ w1aT, unsigned short* __restrict__ w2aT,
                             unsigned short* __restrict__ w1bT, unsigned short* __restrict__ w2bT) {
    int g = blockIdx.x * 256 + threadIdx.x;
    if (g < 32768) {                       // W1aT [128][256]
        int n = g >> 8, k = g & 255;
        w1aT[g] = f2bf(W1a[k * 128 + n]);
    } else if (g < 49152) {                // W2aT [128][128]
        int l = g - 32768; int n = l >> 7, k = l & 127;
        w2aT[l] = f2bf(W2a[k * 128 + n]);
    } else if (g < 98304) {                // W1bT [128][384]
        int l = g - 49152; int n = l / 384, k = l - n * 384;
        w1bT[l] = f2bf(W1b[k * 128 + n]);
    } else if (g < 114688) {               // W2bT [128][128]
        int l = g - 98304; int n = l >> 7, k = l & 127;
        w2bT[l] = f2bf(W2b[k * 128 + n]);
    }
}

// --- edge MLP + LayerNorm + atomic scatter ----------------------------------
__global__ __launch_bounds__(256, 2) void edge_mlp_scatter(
    const float* __restrict__ x, const void* __restrict__ eidx,
    const float* __restrict__ ea,
    const float* __restrict__ b1a, const float* __restrict__ b2a,
    const float* __restrict__ g1, const float* __restrict__ be1,
    const unsigned short* __restrict__ w1aT, const unsigned short* __restrict__ w2aT,
    float* __restrict__ summed, float* __restrict__ counts,
    const int* __restrict__ flag64, int E)
{
    // single aliased region: msg (33792 B) ⊇ h2 (33792 B) ⊇ h1 (17408 B)
    __shared__ union {
        unsigned short msg[64 * 264];   // 64 edges x (256 + 8 pad) bf16  = 33792 B
        unsigned short h1[64 * 136];    // 64 x (128 + 8 pad) bf16        = 17408 B
        float h2[64 * 132];             // 64 x (128 + 4 pad) fp32        = 33792 B
    } uA;
    __shared__ int lsRow[64], lsCol[64];
    __shared__ float sMean[64], sRstd[64];

    const int tid  = threadIdx.x;
    const int lane = tid & 63;
    const int wave = tid >> 6;
    const int quad = lane >> 4;
    const int lm   = lane & 15;
    const int ns   = wave * 32;        // this wave's 32-col n-slice

    // register-resident weight fragments (B-layout: [n=lane&15][k=quad*8+j])
    bf16x8 wf1[8][2], wf2[4][2];
#pragma unroll
    for (int kk = 0; kk < 8; kk++)
#pragma unroll
        for (int nt = 0; nt < 2; nt++)
            wf1[kk][nt] = *(const bf16x8*)(w1aT + (ns + nt * 16 + lm) * 256 + kk * 32 + quad * 8);
#pragma unroll
    for (int kk = 0; kk < 4; kk++)
#pragma unroll
        for (int nt = 0; nt < 2; nt++)
            wf2[kk][nt] = *(const bf16x8*)(w2aT + (ns + nt * 16 + lm) * 128 + kk * 32 + quad * 8);

    float b1v[2], b2v[2];
#pragma unroll
    for (int nt = 0; nt < 2; nt++) {
        b1v[nt] = b1a[ns + nt * 16 + lm];
        b2v[nt] = b2a[ns + nt * 16 + lm];
    }
    const int colT = tid & 127;
    const float gv = g1[colT], bev = be1[colT];
    const int use64 = *flag64;

    const int numTiles = (E + 63) >> 6;
    for (int t = blockIdx.x; t < numTiles; t += gridDim.x) {
        const int eb = t << 6;
        __syncthreads();  // B1: prev tile's scatter readers (h2 + lsRow) done
        if (tid < 64) {
            int e = eb + tid;
            const bool valid = (e < E);
            if (!valid) e = E - 1;
            int r, c;
            if (use64) { const long long* p = (const long long*)eidx; r = (int)p[e]; c = (int)p[E + e]; }
            else       { const int* p = (const int*)eidx;             r = p[e];      c = p[E + e]; }
            lsRow[tid] = r; lsCol[tid] = c;
            if (valid) unsafeAtomicAdd(counts + r, 1.f);
        }
        __syncthreads();  // B2: indices ready
        // ---- stage msg = [x[col] | edge_attr] as bf16 ----
        {
            const int rl = tid >> 5, l32 = tid & 31;
#pragma unroll
            for (int it = 0; it < 8; it++) {
                const int e = it * 8 + rl;
                int eg = eb + e; if (eg >= E) eg = E - 1;
                const float4 xv = ((const float4*)(x + (size_t)lsCol[e] * 128))[l32];
                const float4 av = ((const float4*)(ea + (size_t)eg * 128))[l32];
                *(unsigned int*)&uA.msg[e * 264 + l32 * 4]           = pk2(xv.x, xv.y);
                *(unsigned int*)&uA.msg[e * 264 + l32 * 4 + 2]       = pk2(xv.z, xv.w);
                *(unsigned int*)&uA.msg[e * 264 + 128 + l32 * 4]     = pk2(av.x, av.y);
                *(unsigned int*)&uA.msg[e * 264 + 128 + l32 * 4 + 2] = pk2(av.z, av.w);
            }
        }
        __syncthreads();  // B3: msg ready
        // ---- layer 1: [64x256] @ [256x128] ----
        floatx4 acc1[4][2] = {};
#pragma unroll
        for (int mt = 0; mt < 4; mt++)
#pragma unroll
            for (int kk = 0; kk < 8; kk++) {
                bf16x8 a = *(const bf16x8*)&uA.msg[(mt * 16 + lm) * 264 + kk * 32 + quad * 8];
                acc1[mt][0] = __builtin_amdgcn_mfma_f32_16x16x32_bf16(a, wf1[kk][0], acc1[mt][0], 0, 0, 0);
                acc1[mt][1] = __builtin_amdgcn_mfma_f32_16x16x32_bf16(a, wf1[kk][1], acc1[mt][1], 0, 0, 0);
            }
        __syncthreads();  // B4: all msg reads done (h1 aliases msg region)
        // bias + relu -> h1 (bf16), aliased into msg region
#pragma unroll
        for (int mt = 0; mt < 4; mt++)
#pragma unroll
            for (int nt = 0; nt < 2; nt++)
#pragma unroll
                for (int r = 0; r < 4; r++) {
                    const int row = mt * 16 + quad * 4 + r;
                    const int col = ns + nt * 16 + lm;
                    uA.h1[row * 136 + col] = f2bf(fmaxf(acc1[mt][nt][r] + b1v[nt], 0.f));
                }
        __syncthreads();  // B5: h1 ready
        // ---- layer 2: [64x128] @ [128x128] ----
        floatx4 acc2[4][2] = {};
#pragma unroll
        for (int mt = 0; mt < 4; mt++)
#pragma unroll
            for (int kk = 0; kk < 4; kk++) {
                bf16x8 a = *(const bf16x8*)&uA.h1[(mt * 16 + lm) * 136 + kk * 32 + quad * 8];
                acc2[mt][0] = __builtin_amdgcn_mfma_f32_16x16x32_bf16(a, wf2[kk][0], acc2[mt][0], 0, 0, 0);
                acc2[mt][1] = __builtin_amdgcn_mfma_f32_16x16x32_bf16(a, wf2[kk][1], acc2[mt][1], 0, 0, 0);
            }
        __syncthreads();  // B6: all h1 reads done (h2 overwrites h1 region)
        // + bias -> h2 fp32
#pragma unroll
        for (int mt = 0; mt < 4; mt++)
#pragma unroll
            for (int nt = 0; nt < 2; nt++)
#pragma unroll
                for (int r = 0; r < 4; r++) {
                    const int row = mt * 16 + quad * 4 + r;
                    const int col = ns + nt * 16 + lm;
                    uA.h2[row * 132 + col] = acc2[mt][nt][r] + b2v[nt];
                }
        __syncthreads();  // B7: h2 ready
        // ---- LayerNorm stats: 4 threads per edge ----
        {
            const int e = tid >> 2, q = tid & 3;
            const float4* hp = (const float4*)&uA.h2[e * 132 + q * 32];
            float s = 0.f, ss = 0.f;
#pragma unroll
            for (int i = 0; i < 8; i++) {
                float4 v = hp[i];
                s  += v.x + v.y + v.z + v.w;
                ss += v.x * v.x + v.y * v.y + v.z * v.z + v.w * v.w;
            }
            s  += __shfl_xor(s, 1);  s  += __shfl_xor(s, 2);
            ss += __shfl_xor(ss, 1); ss += __shfl_xor(ss, 2);
            if (q == 0) {
                float mean = s * (1.f / 128.f);
                float var  = ss * (1.f / 128.f) - mean * mean;
                sMean[e] = mean;
                sRstd[e] = rsqrtf(var + 1e-5f);
            }
        }
        __syncthreads();  // B8: stats ready
        // ---- normalized scatter-add (coalesced 128-col runs, HW fp32 atomics) ----
        {
            const int half = tid >> 7;
#pragma unroll
            for (int it = 0; it < 32; it++) {
                const int e = it * 2 + half;
                if (eb + e < E) {
                    float v = (uA.h2[e * 132 + colT] - sMean[e]) * sRstd[e] * gv + bev;
                    unsafeAtomicAdd(summed + (size_t)lsRow[e] * 128 + colT, v);
                }
            }
        }
    }
}

// --- node MLP + LayerNorm -> out --------------------------------------------
__global__ __launch_bounds__(256, 2) void node_mlp(
    const float* __restrict__ x, const float* __restrict__ u,
    const float* summed, const float* __restrict__ counts,
    const float* __restrict__ b1b, const float* __restrict__ b2b,
    const float* __restrict__ g2, const float* __restrict__ be2,
    const unsigned short* __restrict__ w1bT, const unsigned short* __restrict__ w2bT,
    float* out, int NN)
{
    __shared__ union {
        unsigned short msg[32 * 392];   // 32 nodes x (384 + 8 pad) bf16 = 25088 B
        float h2[32 * 132];             // 16896 B
    } uA;
    __shared__ unsigned short h1s[32 * 136];  // 8704 B
    __shared__ float sMean[32], sRstd[32];

    const int tid  = threadIdx.x;
    const int lane = tid & 63;
    const int wave = tid >> 6;
    const int quad = lane >> 4;
    const int lm   = lane & 15;
    const int ns   = wave * 32;

    bf16x8 wf1[12][2], wf2[4][2];
#pragma unroll
    for (int kk = 0; kk < 12; kk++)
#pragma unroll
        for (int nt = 0; nt < 2; nt++)
            wf1[kk][nt] = *(const bf16x8*)(w1bT + (ns + nt * 16 + lm) * 384 + kk * 32 + quad * 8);
#pragma unroll
    for (int kk = 0; kk < 4; kk++)
#pragma unroll
        for (int nt = 0; nt < 2; nt++)
            wf2[kk][nt] = *(const bf16x8*)(w2bT + (ns + nt * 16 + lm) * 128 + kk * 32 + quad * 8);

    float b1v[2], b2v[2];
#pragma unroll
    for (int nt = 0; nt < 2; nt++) {
        b1v[nt] = b1b[ns + nt * 16 + lm];
        b2v[nt] = b2b[ns + nt * 16 + lm];
    }
    const int colT = tid & 127;
    const float gv = g2[colT], bev = be2[colT];

    const int numTiles = (NN + 31) >> 5;
    for (int t = blockIdx.x; t < numTiles; t += gridDim.x) {
        const int nb = t << 5;
        __syncthreads();
        // ---- stage z = [x | summed/clip(counts,1) | u] as bf16 ----
        {
            const int rl = tid >> 5, l32 = tid & 31;
#pragma unroll
            for (int it = 0; it < 4; it++) {
                const int rloc = it * 8 + rl;
                int i = nb + rloc; if (i >= NN) i = NN - 1;
                const float4 xv = ((const float4*)(x + (size_t)i * 128))[l32];
                float4 sv = ((const float4*)(summed + (size_t)i * 128))[l32];
                const float inv = 1.f / fmaxf(counts[i], 1.f);
                sv.x *= inv; sv.y *= inv; sv.z *= inv; sv.w *= inv;
                const float4 uv = ((const float4*)(u + (size_t)i * 128))[l32];
                *(unsigned int*)&uA.msg[rloc * 392 + l32 * 4]           = pk2(xv.x, xv.y);
                *(unsigned int*)&uA.msg[rloc * 392 + l32 * 4 + 2]       = pk2(xv.z, xv.w);
                *(unsigned int*)&uA.msg[rloc * 392 + 128 + l32 * 4]     = pk2(sv.x, sv.y);
                *(unsigned int*)&uA.msg[rloc * 392 + 128 + l32 * 4 + 2] = pk2(sv.z, sv.w);
                *(unsigned int*)&uA.msg[rloc * 392 + 256 + l32 * 4]     = pk2(uv.x, uv.y);
                *(unsigned int*)&uA.msg[rloc * 392 + 256 + l32 * 4 + 2] = pk2(uv.z, uv.w);
            }
        }
        __syncthreads();
        // ---- layer 1: [32x384] @ [384x128] ----
        floatx4 acc1[2][2] = {};
#pragma unroll
        for (int mt = 0; mt < 2; mt++)
#pragma unroll
            for (int kk = 0; kk < 12; kk++) {
                bf16x8 a = *(const bf16x8*)&uA.msg[(mt * 16 + lm) * 392 + kk * 32 + quad * 8];
                acc1[mt][0] = __builtin_amdgcn_mfma_f32_16x16x32_bf16(a, wf1[kk][0], acc1[mt][0], 0, 0, 0);
                acc1[mt][1] = __builtin_amdgcn_mfma_f32_16x16x32_bf16(a, wf1[kk][1], acc1[mt][1], 0, 0, 0);
            }
#pragma unroll
        for (int mt = 0; mt < 2; mt++)
#pragma unroll
            for (int nt = 0; nt < 2; nt++)
#pragma unroll
                for (int r = 0; r < 4; r++) {
                    const int row = mt * 16 + quad * 4 + r;
                    const int col = ns + nt * 16 + lm;
                    h1s[row * 136 + col] = f2bf(fmaxf(acc1[mt][nt][r] + b1v[nt], 0.f));
                }
        __syncthreads();
        // ---- layer 2: [32x128] @ [128x128] ----
        floatx4 acc2[2][2] = {};
#pragma unroll
        for (int mt = 0; mt < 2; mt++)
#pragma unroll
            for (int kk = 0; kk < 4; kk++) {
                bf16x8 a = *(const bf16x8*)&h1s[(mt * 16 + lm) * 136 + kk * 32 + quad * 8];
                acc2[mt][0] = __builtin_amdgcn_mfma_f32_16x16x32_bf16(a, wf2[kk][0], acc2[mt][0], 0, 0, 0);
                acc2[mt][1] = __builtin_amdgcn_mfma_f32_16x16x32_bf16(a, wf2[kk][1], acc2[mt][1], 0, 0, 0);
            }
#pragma unroll
        for (int mt = 0; mt < 2; mt++)
#pragma unroll
            for (int nt = 0; nt < 2; nt++)
#pragma unroll
                for (int r = 0; r < 4; r++) {
                    const int row = mt * 16 + quad * 4 + r;
                    const int col = ns + nt * 16 + lm;
                    uA.h2[row * 132 + col] = acc2[mt][nt][r] + b2v[nt];
                }
        __syncthreads();
        // ---- LayerNorm stats: 8 threads per node ----
        {
            const int e = tid >> 3, q = tid & 7;
            const float4* hp = (const float4*)&uA.h2[e * 132 + q * 16];
            float s = 0.f, ss = 0.f;
#pragma unroll
            for (int i = 0; i < 4; i++) {
                float4 v = hp[i];
                s  += v.x + v.y + v.z + v.w;
                ss += v.x * v.x + v.y * v.y + v.z * v.z + v.w * v.w;
            }
            s  += __shfl_xor(s, 1);  s  += __shfl_xor(s, 2);  s  += __shfl_xor(s, 4);
            ss += __shfl_xor(ss, 1); ss += __shfl_xor(ss, 2); ss += __shfl_xor(ss, 4);
            if (q == 0) {
                float mean = s * (1.f / 128.f);
                float var  = ss * (1.f / 128.f) - mean * mean;
                sMean[e] = mean;
                sRstd[e] = rsqrtf(var + 1e-5f);
            }
        }
        __syncthreads();
        // ---- normalized coalesced store ----
        {
            const int half = tid >> 7;
#pragma unroll
            for (int it = 0; it < 16; it++) {
                const int rloc = it * 2 + half;
                const int i = nb + rloc;
                if (i < NN) {
                    float v = (uA.h2[rloc * 132 + colT] - sMean[rloc]) * sRstd[rloc] * gv + bev;
                    out[(size_t)i * 128 + colT] = v;
                }
            }
        }
    }
}

extern "C" void kernel_launch(void* const* d_in, const int* in_sizes, int n_in,
                              void* d_out, int out_size, void* d_ws, size_t ws_size,
                              hipStream_t stream)
{
    const float* x   = (const float*)d_in[0];
    const void*  eidx = d_in[1];
    const float* ea  = (const float*)d_in[2];
    const float* u   = (const float*)d_in[3];
    const float* W1a = (const float*)d_in[4];
    const float* b1a = (const float*)d_in[5];
    const float* W2a = (const float*)d_in[6];
    const float* b2a = (const float*)d_in[7];
    const float* g1  = (const float*)d_in[8];
    const float* be1 = (const float*)d_in[9];
    const float* W1b = (const float*)d_in[10];
    const float* b1b = (const float*)d_in[11];
    const float* W2b = (const float*)d_in[12];
    const float* b2b = (const float*)d_in[13];
    const float* g2  = (const float*)d_in[14];
    const float* be2 = (const float*)d_in[15];

    const int NN = in_sizes[0] / 128;
    const int E  = in_sizes[2] / 128;

    // workspace layout: counts[N] | flag | bf16 transposed weights
    float* counts = (float*)d_ws;
    int*   flag   = (int*)((char*)d_ws + (size_t)NN * 4);
    size_t woff   = (((size_t)NN * 4 + 4) + 15) & ~(size_t)15;
    unsigned short* w1aT = (unsigned short*)((char*)d_ws + woff);
    unsigned short* w2aT = w1aT + 128 * 256;
    unsigned short* w1bT = w2aT + 128 * 128;
    unsigned short* w2bT = w1bT + 128 * 384;

    float* outf = (float*)d_out;   // doubles as the scatter-sum buffer

    hipMemsetAsync(d_out, 0, (size_t)out_size * 4, stream);
    hipMemsetAsync(counts, 0, (size_t)NN * 4, stream);
    detect_idx64<<<1, 64, 0, stream>>>((const unsigned int*)eidx, flag);
    prep_weights<<<448, 256, 0, stream>>>(W1a, W2a, W1b, W2b, w1aT, w2aT, w1bT, w2bT);

    edge_mlp_scatter<<<1024, 256, 0, stream>>>(x, eidx, ea, b1a, b2a, g1, be1,
                                               w1aT, w2aT, outf, counts, flag, E);

    const int nodeTiles = (NN + 31) >> 5;
    node_mlp<<<nodeTiles, 256, 0, stream>>>(x, u, outf, counts, b1b, b2b, g2, be2,
                                            w1bT, w2bT, outf, NN);
}

// Round 3
// 795.628 us; speedup vs baseline: 1.3978x; 1.2686x over previous
//
#include <hip/hip_runtime.h>
#include <hip/hip_fp16.h>

// ---------------------------------------------------------------------------
// NodeModelLtp: edge MLP (Linear(256->128)+ReLU, Linear(128->128), LN) ->
// scatter-mean over dst -> node MLP (Linear(384->128)+ReLU, Linear(128->128), LN)
// bf16 MFMA (16x16x32) with fp32 accumulate; weights register-resident.
//
// R3 changes vs R2 (1009 us):
//  - REVERT LDS aliasing (R0 6-barrier structure, separate h1s): R2's aliasing
//    raised SQ_LDS_BANK_CONFLICT 4.6e7 -> 6.2e7 (+~26us/CU) and added 2
//    barriers for zero occupancy gain (occupancy is VGPR+AGPR-limited at
//    ~192 regs -> 2 blocks/CU regardless of LDS).
//  - PACKED f16 atomics for the scatter: global_atomic_pk_add_f16 via
//    unsafeAtomicAdd(__half2*). Halves atomic op count (102M -> 51M) and
//    atomic write traffic. summed becomes __half[N][128] in d_ws, with a
//    host-side ws_size check and fp32-into-d_out fallback (zero crash risk).
//  - node_mlp: 512 persistent blocks x ~3 tiles (was 1563 x 1) to amortize
//    the ~128-VGPR weight-fragment setup; should surface in top-5 profile.
// ---------------------------------------------------------------------------

typedef __bf16 bf16x8 __attribute__((ext_vector_type(8)));
typedef float floatx4 __attribute__((ext_vector_type(4)));

__device__ __forceinline__ unsigned short f2bf(float f) {
    unsigned int u = __float_as_uint(f);
    u = u + 0x7FFFu + ((u >> 16) & 1u);   // RNE
    return (unsigned short)(u >> 16);
}
__device__ __forceinline__ unsigned int pk2(float a, float b) {
    return (unsigned int)f2bf(a) | ((unsigned int)f2bf(b) << 16);
}

// --- detect whether edge_idx buffer is int64 (odd 32-bit words all zero) ----
__global__ void detect_idx64(const unsigned int* __restrict__ idx, int* __restrict__ flag) {
    if (threadIdx.x == 0 && blockIdx.x == 0) {
        unsigned int o = 0;
        for (int i = 1; i < 64; i += 2) o |= idx[i];
        *flag = (o == 0u) ? 1 : 0;
    }
}

// --- convert + transpose weights to bf16 [n][K] -----------------------------
__global__ void prep_weights(const float* __restrict__ W1a, const float* __restrict__ W2a,
                             const float* __restrict__ W1b, const float* __restrict__ W2b,
                             unsigned short* __restrict__ w1aT, unsigned short* __restrict__ w2aT,
                             unsigned short* __restrict__ w1bT, unsigned short* __restrict__ w2bT) {
    int g = blockIdx.x * 256 + threadIdx.x;
    if (g < 32768) {                       // W1aT [128][256]
        int n = g >> 8, k = g & 255;
        w1aT[g] = f2bf(W1a[k * 128 + n]);
    } else if (g < 49152) {                // W2aT [128][128]
        int l = g - 32768; int n = l >> 7, k = l & 127;
        w2aT[l] = f2bf(W2a[k * 128 + n]);
    } else if (g < 98304) {                // W1bT [128][384]
        int l = g - 49152; int n = l / 384, k = l - n * 384;
        w1bT[l] = f2bf(W1b[k * 128 + n]);
    } else if (g < 114688) {               // W2bT [128][128]
        int l = g - 98304; int n = l >> 7, k = l & 127;
        w2bT[l] = f2bf(W2b[k * 128 + n]);
    }
}

// --- edge MLP + LayerNorm + atomic scatter ----------------------------------
__global__ __launch_bounds__(256, 2) void edge_mlp_scatter(
    const float* __restrict__ x, const void* __restrict__ eidx,
    const float* __restrict__ ea,
    const float* __restrict__ b1a, const float* __restrict__ b2a,
    const float* __restrict__ g1, const float* __restrict__ be1,
    const unsigned short* __restrict__ w1aT, const unsigned short* __restrict__ w2aT,
    float* __restrict__ summed, __half* __restrict__ summedH,
    float* __restrict__ counts,
    const int* __restrict__ flag64, int E, int useHalf)
{
    __shared__ union {
        unsigned short msg[64 * 264];   // 64 edges x (256 + 8 pad) bf16  = 33792 B
        float h2[64 * 132];             // 64 x (128 + 4 pad) fp32        = 33792 B
    } uA;
    __shared__ unsigned short h1s[64 * 136];  // 17408 B (separate: no alias conflicts)
    __shared__ int lsRow[64], lsCol[64];
    __shared__ float sMean[64], sRstd[64];

    const int tid  = threadIdx.x;
    const int lane = tid & 63;
    const int wave = tid >> 6;
    const int quad = lane >> 4;
    const int lm   = lane & 15;
    const int ns   = wave * 32;        // this wave's 32-col n-slice

    // register-resident weight fragments (B-layout: [n=lane&15][k=quad*8+j])
    bf16x8 wf1[8][2], wf2[4][2];
#pragma unroll
    for (int kk = 0; kk < 8; kk++)
#pragma unroll
        for (int nt = 0; nt < 2; nt++)
            wf1[kk][nt] = *(const bf16x8*)(w1aT + (ns + nt * 16 + lm) * 256 + kk * 32 + quad * 8);
#pragma unroll
    for (int kk = 0; kk < 4; kk++)
#pragma unroll
        for (int nt = 0; nt < 2; nt++)
            wf2[kk][nt] = *(const bf16x8*)(w2aT + (ns + nt * 16 + lm) * 128 + kk * 32 + quad * 8);

    float b1v[2], b2v[2];
#pragma unroll
    for (int nt = 0; nt < 2; nt++) {
        b1v[nt] = b1a[ns + nt * 16 + lm];
        b2v[nt] = b2a[ns + nt * 16 + lm];
    }
    // fp32-path epilogue params (one col per thread)
    const int colT = tid & 127;
    const float gv = g1[colT], bev = be1[colT];
    // f16-path epilogue params (col pair per thread)
    const int colP = tid & 63, eg4 = tid >> 6;
    float gA = 0.f, gB = 0.f, bA = 0.f, bB = 0.f;
    if (useHalf) {
        gA = g1[colP * 2];  gB = g1[colP * 2 + 1];
        bA = be1[colP * 2]; bB = be1[colP * 2 + 1];
    }
    const int use64 = *flag64;

    const int numTiles = (E + 63) >> 6;
    for (int t = blockIdx.x; t < numTiles; t += gridDim.x) {
        const int eb = t << 6;
        __syncthreads();  // B1: prev tile's scatter readers (h2 + lsRow) done
        if (tid < 64) {
            int e = eb + tid; if (e >= E) e = E - 1;
            int r, c;
            if (use64) { const long long* p = (const long long*)eidx; r = (int)p[e]; c = (int)p[E + e]; }
            else       { const int* p = (const int*)eidx;             r = p[e];      c = p[E + e]; }
            lsRow[tid] = r; lsCol[tid] = c;
        }
        __syncthreads();  // B2: indices ready
        // ---- stage msg = [x[col] | edge_attr] as bf16 ----
        {
            const int rl = tid >> 5, l32 = tid & 31;
#pragma unroll
            for (int it = 0; it < 8; it++) {
                const int e = it * 8 + rl;
                int eg = eb + e; if (eg >= E) eg = E - 1;
                const float4 xv = ((const float4*)(x + (size_t)lsCol[e] * 128))[l32];
                const float4 av = ((const float4*)(ea + (size_t)eg * 128))[l32];
                *(unsigned int*)&uA.msg[e * 264 + l32 * 4]           = pk2(xv.x, xv.y);
                *(unsigned int*)&uA.msg[e * 264 + l32 * 4 + 2]       = pk2(xv.z, xv.w);
                *(unsigned int*)&uA.msg[e * 264 + 128 + l32 * 4]     = pk2(av.x, av.y);
                *(unsigned int*)&uA.msg[e * 264 + 128 + l32 * 4 + 2] = pk2(av.z, av.w);
            }
        }
        __syncthreads();  // B3: msg ready
        // ---- layer 1: [64x256] @ [256x128] ----
        floatx4 acc1[4][2] = {};
#pragma unroll
        for (int mt = 0; mt < 4; mt++)
#pragma unroll
            for (int kk = 0; kk < 8; kk++) {
                bf16x8 a = *(const bf16x8*)&uA.msg[(mt * 16 + lm) * 264 + kk * 32 + quad * 8];
                acc1[mt][0] = __builtin_amdgcn_mfma_f32_16x16x32_bf16(a, wf1[kk][0], acc1[mt][0], 0, 0, 0);
                acc1[mt][1] = __builtin_amdgcn_mfma_f32_16x16x32_bf16(a, wf1[kk][1], acc1[mt][1], 0, 0, 0);
            }
        // bias + relu -> h1 (bf16, separate buffer — no barrier needed)
#pragma unroll
        for (int mt = 0; mt < 4; mt++)
#pragma unroll
            for (int nt = 0; nt < 2; nt++)
#pragma unroll
                for (int r = 0; r < 4; r++) {
                    const int row = mt * 16 + quad * 4 + r;
                    const int col = ns + nt * 16 + lm;
                    h1s[row * 136 + col] = f2bf(fmaxf(acc1[mt][nt][r] + b1v[nt], 0.f));
                }
        __syncthreads();  // B4: h1 ready (and all msg reads done)
        // ---- layer 2: [64x128] @ [128x128] ----
        floatx4 acc2[4][2] = {};
#pragma unroll
        for (int mt = 0; mt < 4; mt++)
#pragma unroll
            for (int kk = 0; kk < 4; kk++) {
                bf16x8 a = *(const bf16x8*)&h1s[(mt * 16 + lm) * 136 + kk * 32 + quad * 8];
                acc2[mt][0] = __builtin_amdgcn_mfma_f32_16x16x32_bf16(a, wf2[kk][0], acc2[mt][0], 0, 0, 0);
                acc2[mt][1] = __builtin_amdgcn_mfma_f32_16x16x32_bf16(a, wf2[kk][1], acc2[mt][1], 0, 0, 0);
            }
        // + bias -> h2 fp32 (reuses msg area; msg readers done at B4)
#pragma unroll
        for (int mt = 0; mt < 4; mt++)
#pragma unroll
            for (int nt = 0; nt < 2; nt++)
#pragma unroll
                for (int r = 0; r < 4; r++) {
                    const int row = mt * 16 + quad * 4 + r;
                    const int col = ns + nt * 16 + lm;
                    uA.h2[row * 132 + col] = acc2[mt][nt][r] + b2v[nt];
                }
        __syncthreads();  // B5: h2 ready
        // ---- LayerNorm stats: 4 threads per edge (+ counts atomic) ----
        {
            const int e = tid >> 2, q = tid & 3;
            const float4* hp = (const float4*)&uA.h2[e * 132 + q * 32];
            float s = 0.f, ss = 0.f;
#pragma unroll
            for (int i = 0; i < 8; i++) {
                float4 v = hp[i];
                s  += v.x + v.y + v.z + v.w;
                ss += v.x * v.x + v.y * v.y + v.z * v.z + v.w * v.w;
            }
            s  += __shfl_xor(s, 1);  s  += __shfl_xor(s, 2);
            ss += __shfl_xor(ss, 1); ss += __shfl_xor(ss, 2);
            if (q == 0) {
                float mean = s * (1.f / 128.f);
                float var  = ss * (1.f / 128.f) - mean * mean;
                sMean[e] = mean;
                sRstd[e] = rsqrtf(var + 1e-5f);
                if (eb + e < E) unsafeAtomicAdd(counts + lsRow[e], 1.f);
            }
        }
        __syncthreads();  // B6: stats ready
        // ---- normalized scatter-add ----
        if (useHalf) {
            // packed f16 atomics: 64 half2 ops per edge row (halved op count)
#pragma unroll
            for (int it = 0; it < 16; it++) {
                const int e = it * 4 + eg4;
                if (eb + e < E) {
                    const float2 h = *(const float2*)&uA.h2[e * 132 + colP * 2];
                    const float m = sMean[e], rs = sRstd[e];
                    const float v0 = (h.x - m) * rs * gA + bA;
                    const float v1 = (h.y - m) * rs * gB + bB;
                    unsafeAtomicAdd((__half2*)(summedH + (size_t)lsRow[e] * 128 + colP * 2),
                                    __floats2half2_rn(v0, v1));
                }
            }
        } else {
#pragma unroll
            for (int it = 0; it < 32; it++) {
                const int e = it * 2 + (tid >> 7);
                if (eb + e < E) {
                    float v = (uA.h2[e * 132 + colT] - sMean[e]) * sRstd[e] * gv + bev;
                    unsafeAtomicAdd(summed + (size_t)lsRow[e] * 128 + colT, v);
                }
            }
        }
    }
}

// --- node MLP + LayerNorm -> out --------------------------------------------
__global__ __launch_bounds__(256, 2) void node_mlp(
    const float* __restrict__ x, const float* __restrict__ u,
    const float* summed, const __half* __restrict__ summedH,
    const float* __restrict__ counts,
    const float* __restrict__ b1b, const float* __restrict__ b2b,
    const float* __restrict__ g2, const float* __restrict__ be2,
    const unsigned short* __restrict__ w1bT, const unsigned short* __restrict__ w2bT,
    float* out, int NN, int useHalf)
{
    __shared__ union {
        unsigned short msg[32 * 392];   // 32 nodes x (384 + 8 pad) bf16 = 25088 B
        float h2[32 * 132];             // 16896 B
    } uA;
    __shared__ unsigned short h1s[32 * 136];  // 8704 B
    __shared__ float sMean[32], sRstd[32];

    const int tid  = threadIdx.x;
    const int lane = tid & 63;
    const int wave = tid >> 6;
    const int quad = lane >> 4;
    const int lm   = lane & 15;
    const int ns   = wave * 32;

    bf16x8 wf1[12][2], wf2[4][2];
#pragma unroll
    for (int kk = 0; kk < 12; kk++)
#pragma unroll
        for (int nt = 0; nt < 2; nt++)
            wf1[kk][nt] = *(const bf16x8*)(w1bT + (ns + nt * 16 + lm) * 384 + kk * 32 + quad * 8);
#pragma unroll
    for (int kk = 0; kk < 4; kk++)
#pragma unroll
        for (int nt = 0; nt < 2; nt++)
            wf2[kk][nt] = *(const bf16x8*)(w2bT + (ns + nt * 16 + lm) * 128 + kk * 32 + quad * 8);

    float b1v[2], b2v[2];
#pragma unroll
    for (int nt = 0; nt < 2; nt++) {
        b1v[nt] = b1b[ns + nt * 16 + lm];
        b2v[nt] = b2b[ns + nt * 16 + lm];
    }
    const int colT = tid & 127;
    const float gv = g2[colT], bev = be2[colT];

    const int numTiles = (NN + 31) >> 5;
    for (int t = blockIdx.x; t < numTiles; t += gridDim.x) {
        const int nb = t << 5;
        __syncthreads();
        // ---- stage z = [x | summed/clip(counts,1) | u] as bf16 ----
        {
            const int rl = tid >> 5, l32 = tid & 31;
#pragma unroll
            for (int it = 0; it < 4; it++) {
                const int rloc = it * 8 + rl;
                int i = nb + rloc; if (i >= NN) i = NN - 1;
                const float4 xv = ((const float4*)(x + (size_t)i * 128))[l32];
                float4 sv;
                if (useHalf) {
                    const float2 rw = ((const float2*)(summedH + (size_t)i * 128))[l32];
                    const __half2 h01 = *(const __half2*)&rw.x;
                    const __half2 h23 = *(const __half2*)&rw.y;
                    const float2 a = __half22float2(h01);
                    const float2 b = __half22float2(h23);
                    sv.x = a.x; sv.y = a.y; sv.z = b.x; sv.w = b.y;
                } else {
                    sv = ((const float4*)(summed + (size_t)i * 128))[l32];
                }
                const float inv = 1.f / fmaxf(counts[i], 1.f);
                sv.x *= inv; sv.y *= inv; sv.z *= inv; sv.w *= inv;
                const float4 uv = ((const float4*)(u + (size_t)i * 128))[l32];
                *(unsigned int*)&uA.msg[rloc * 392 + l32 * 4]           = pk2(xv.x, xv.y);
                *(unsigned int*)&uA.msg[rloc * 392 + l32 * 4 + 2]       = pk2(xv.z, xv.w);
                *(unsigned int*)&uA.msg[rloc * 392 + 128 + l32 * 4]     = pk2(sv.x, sv.y);
                *(unsigned int*)&uA.msg[rloc * 392 + 128 + l32 * 4 + 2] = pk2(sv.z, sv.w);
                *(unsigned int*)&uA.msg[rloc * 392 + 256 + l32 * 4]     = pk2(uv.x, uv.y);
                *(unsigned int*)&uA.msg[rloc * 392 + 256 + l32 * 4 + 2] = pk2(uv.z, uv.w);
            }
        }
        __syncthreads();
        // ---- layer 1: [32x384] @ [384x128] ----
        floatx4 acc1[2][2] = {};
#pragma unroll
        for (int mt = 0; mt < 2; mt++)
#pragma unroll
            for (int kk = 0; kk < 12; kk++) {
                bf16x8 a = *(const bf16x8*)&uA.msg[(mt * 16 + lm) * 392 + kk * 32 + quad * 8];
                acc1[mt][0] = __builtin_amdgcn_mfma_f32_16x16x32_bf16(a, wf1[kk][0], acc1[mt][0], 0, 0, 0);
                acc1[mt][1] = __builtin_amdgcn_mfma_f32_16x16x32_bf16(a, wf1[kk][1], acc1[mt][1], 0, 0, 0);
            }
#pragma unroll
        for (int mt = 0; mt < 2; mt++)
#pragma unroll
            for (int nt = 0; nt < 2; nt++)
#pragma unroll
                for (int r = 0; r < 4; r++) {
                    const int row = mt * 16 + quad * 4 + r;
                    const int col = ns + nt * 16 + lm;
                    h1s[row * 136 + col] = f2bf(fmaxf(acc1[mt][nt][r] + b1v[nt], 0.f));
                }
        __syncthreads();
        // ---- layer 2: [32x128] @ [128x128] ----
        floatx4 acc2[2][2] = {};
#pragma unroll
        for (int mt = 0; mt < 2; mt++)
#pragma unroll
            for (int kk = 0; kk < 4; kk++) {
                bf16x8 a = *(const bf16x8*)&h1s[(mt * 16 + lm) * 136 + kk * 32 + quad * 8];
                acc2[mt][0] = __builtin_amdgcn_mfma_f32_16x16x32_bf16(a, wf2[kk][0], acc2[mt][0], 0, 0, 0);
                acc2[mt][1] = __builtin_amdgcn_mfma_f32_16x16x32_bf16(a, wf2[kk][1], acc2[mt][1], 0, 0, 0);
            }
#pragma unroll
        for (int mt = 0; mt < 2; mt++)
#pragma unroll
            for (int nt = 0; nt < 2; nt++)
#pragma unroll
                for (int r = 0; r < 4; r++) {
                    const int row = mt * 16 + quad * 4 + r;
                    const int col = ns + nt * 16 + lm;
                    uA.h2[row * 132 + col] = acc2[mt][nt][r] + b2v[nt];
                }
        __syncthreads();
        // ---- LayerNorm stats: 8 threads per node ----
        {
            const int e = tid >> 3, q = tid & 7;
            const float4* hp = (const float4*)&uA.h2[e * 132 + q * 16];
            float s = 0.f, ss = 0.f;
#pragma unroll
            for (int i = 0; i < 4; i++) {
                float4 v = hp[i];
                s  += v.x + v.y + v.z + v.w;
                ss += v.x * v.x + v.y * v.y + v.z * v.z + v.w * v.w;
            }
            s  += __shfl_xor(s, 1);  s  += __shfl_xor(s, 2);  s  += __shfl_xor(s, 4);
            ss += __shfl_xor(ss, 1); ss += __shfl_xor(ss, 2); ss += __shfl_xor(ss, 4);
            if (q == 0) {
                float mean = s * (1.f / 128.f);
                float var  = ss * (1.f / 128.f) - mean * mean;
                sMean[e] = mean;
                sRstd[e] = rsqrtf(var + 1e-5f);
            }
        }
        __syncthreads();
        // ---- normalized coalesced store ----
        {
            const int half = tid >> 7;
#pragma unroll
            for (int it = 0; it < 16; it++) {
                const int rloc = it * 2 + half;
                const int i = nb + rloc;
                if (i < NN) {
                    float v = (uA.h2[rloc * 132 + colT] - sMean[rloc]) * sRstd[rloc] * gv + bev;
                    out[(size_t)i * 128 + colT] = v;
                }
            }
        }
    }
}

extern "C" void kernel_launch(void* const* d_in, const int* in_sizes, int n_in,
                              void* d_out, int out_size, void* d_ws, size_t ws_size,
                              hipStream_t stream)
{
    const float* x   = (const float*)d_in[0];
    const void*  eidx = d_in[1];
    const float* ea  = (const float*)d_in[2];
    const float* u   = (const float*)d_in[3];
    const float* W1a = (const float*)d_in[4];
    const float* b1a = (const float*)d_in[5];
    const float* W2a = (const float*)d_in[6];
    const float* b2a = (const float*)d_in[7];
    const float* g1  = (const float*)d_in[8];
    const float* be1 = (const float*)d_in[9];
    const float* W1b = (const float*)d_in[10];
    const float* b1b = (const float*)d_in[11];
    const float* W2b = (const float*)d_in[12];
    const float* b2b = (const float*)d_in[13];
    const float* g2  = (const float*)d_in[14];
    const float* be2 = (const float*)d_in[15];

    const int NN = in_sizes[0] / 128;
    const int E  = in_sizes[2] / 128;

    // workspace layout: counts[N] | flag | bf16 weights | (optional) f16 summed
    float* counts = (float*)d_ws;
    int*   flag   = (int*)((char*)d_ws + (size_t)NN * 4);
    size_t woff   = (((size_t)NN * 4 + 4) + 15) & ~(size_t)15;
    unsigned short* w1aT = (unsigned short*)((char*)d_ws + woff);
    unsigned short* w2aT = w1aT + 128 * 256;
    unsigned short* w1bT = w2aT + 128 * 128;
    unsigned short* w2bT = w1bT + 128 * 384;
    size_t shoff  = (woff + (size_t)(128*256 + 128*128 + 128*384 + 128*128) * 2 + 255) & ~(size_t)255;
    __half* summedH = (__half*)((char*)d_ws + shoff);
    const int useHalf = (ws_size >= shoff + (size_t)NN * 128 * 2) ? 1 : 0;

    float* outf = (float*)d_out;   // fp32 fallback: doubles as the scatter-sum buffer

    if (useHalf) {
        hipMemsetAsync(summedH, 0, (size_t)NN * 128 * 2, stream);
    } else {
        hipMemsetAsync(d_out, 0, (size_t)out_size * 4, stream);
    }
    hipMemsetAsync(counts, 0, (size_t)NN * 4, stream);
    detect_idx64<<<1, 64, 0, stream>>>((const unsigned int*)eidx, flag);
    prep_weights<<<448, 256, 0, stream>>>(W1a, W2a, W1b, W2b, w1aT, w2aT, w1bT, w2bT);

    edge_mlp_scatter<<<512, 256, 0, stream>>>(x, eidx, ea, b1a, b2a, g1, be1,
                                              w1aT, w2aT, outf, summedH, counts, flag, E, useHalf);

    node_mlp<<<512, 256, 0, stream>>>(x, u, outf, summedH, counts, b1b, b2b, g2, be2,
                                      w1bT, w2bT, outf, NN, useHalf);
}